// Round 7
// baseline (202.493 us; speedup 1.0000x reference)
//
#include <hip/hip_runtime.h>

// N=8192 nodes, D=512, E=262144. NEG=-1e6 => exp underflows to exactly 0,
// so softmax is EXACTLY sparse over each row's neighbor set (bitmask dedupes
// duplicate edges, matching .at[].set(1.0) idempotence).
//
// R7: gemm = register-direct MFMA (NO LDS staging, no K-loop barriers; A/B
//     frags global->VGPR, L2-resident via XCD swizzle, L1 catches wave-pair
//     reuse). k|v interleaved per node (one 2KB block per edge gather).
//     Edge scatter merged into the gemm launch. attn = R6 fused single-pass.

#define N_NODES 8192
#define DIM 512
#define MASK_WORDS 256   // 8192 bits / 32
#define CAPW 512         // per-wave neighbor chunk capacity
#define KV_STRIDE 1024   // ushorts per node in interleaved k|v buffer

typedef __attribute__((ext_vector_type(8))) short short8;
typedef __attribute__((ext_vector_type(4))) float f32x4;

__device__ __forceinline__ unsigned short f2bf(float f) {
    unsigned int u = __float_as_uint(f);
    u += 0x7fffu + ((u >> 16) & 1u);          // round-to-nearest-even
    return (unsigned short)(u >> 16);
}
__device__ __forceinline__ float bf_lo(unsigned int w) { return __uint_as_float(w << 16); }
__device__ __forceinline__ float bf_hi(unsigned int w) { return __uint_as_float(w & 0xffff0000u); }

__device__ __forceinline__ float wred_sum(float s) {
    #pragma unroll
    for (int off = 1; off <= 32; off <<= 1) s += __shfl_xor(s, off, 64);
    return s;
}
__device__ __forceinline__ int wred_sumi(int s) {
    #pragma unroll
    for (int off = 1; off <= 32; off <<= 1) s += __shfl_xor(s, off, 64);
    return s;
}
__device__ __forceinline__ float dot8(uint4 a, uint4 b) {
    return bf_lo(a.x) * bf_lo(b.x) + bf_hi(a.x) * bf_hi(b.x)
         + bf_lo(a.y) * bf_lo(b.y) + bf_hi(a.y) * bf_hi(b.y)
         + bf_lo(a.z) * bf_lo(b.z) + bf_hi(a.z) * bf_hi(b.z)
         + bf_lo(a.w) * bf_lo(b.w) + bf_hi(a.w) * bf_hi(b.w);
}

// ---------------------------------------------------------------------------
// prep1: [0,4096) convert x -> bf16 AND zero 2KB of mask each |
//        [4096,4864) transpose-convert W -> Wt
// ---------------------------------------------------------------------------
__global__ __launch_bounds__(256) void prep1(
    const float* __restrict__ x, unsigned short* __restrict__ xb,
    const float* __restrict__ Wq, const float* __restrict__ Wk,
    const float* __restrict__ Wv, unsigned short* __restrict__ Wt,
    unsigned int* __restrict__ mask)
{
    __shared__ float sm[32][33];
    const int b = blockIdx.x;
    if (b < 4096) {
        int i = b * 256 + threadIdx.x;
        float4 f = ((const float4*)x)[i];
        ushort4 o;
        o.x = f2bf(f.x); o.y = f2bf(f.y); o.z = f2bf(f.z); o.w = f2bf(f.w);
        ((ushort4*)xb)[i] = o;
        ((uint2*)mask)[i] = make_uint2(0u, 0u);     // 4096*256*8B = 8MB
    } else {
        int bb = b - 4096;
        int which = bb >> 8, t = bb & 255;
        const float* __restrict__ W = (which == 0) ? Wq : (which == 1) ? Wk : Wv;
        unsigned short* __restrict__ outp = Wt + (size_t)which * DIM * DIM;
        int n0 = (t & 15) * 32, k0 = (t >> 4) * 32;
        int tx = threadIdx.x & 31, ty = threadIdx.x >> 5;
        #pragma unroll
        for (int r = 0; r < 4; ++r)
            sm[ty + 8 * r][tx] = W[(size_t)(k0 + ty + 8 * r) * DIM + n0 + tx];
        __syncthreads();
        #pragma unroll
        for (int r = 0; r < 4; ++r)
            outp[(size_t)(n0 + ty + 8 * r) * DIM + k0 + tx] = f2bf(sm[tx][ty + 8 * r]);
    }
}

// ---------------------------------------------------------------------------
// gemm + edge scatter in one launch (both depend only on prep1).
// blocks [0,768): bf16 MFMA GEMM, 128x128 tile, register-direct fragments
//   (no LDS staging, no K-loop barriers). XCD swizzle keeps the per-XCD A
//   slice (1MB) + all B (1.5MB) L2-resident; L1 catches wave-pair reuse.
//   q written at stride 512; k,v interleaved per node at stride 1024.
// blocks [768,...): scatter edges into bitmask.
// ---------------------------------------------------------------------------
__global__ __launch_bounds__(256) void gemm_scatter(
    const unsigned short* __restrict__ xb, const unsigned short* __restrict__ Wt,
    const float* __restrict__ bq, const float* __restrict__ bk, const float* __restrict__ bv,
    unsigned short* __restrict__ qb, unsigned short* __restrict__ kv,
    const int* __restrict__ ei, unsigned int* __restrict__ mask, int E)
{
    __shared__ unsigned short tb[64 * 128];   // epilogue transpose only (16KB)

    const int tid = threadIdx.x;

    if (blockIdx.x >= 768) {
        int e = (blockIdx.x - 768) * 256 + tid;
        if (e < E) {
            int src = ei[e];
            int dst = ei[E + e];
            atomicOr(&mask[(size_t)src * MASK_WORDS + (dst >> 5)], 1u << (dst & 31));
        }
        return;
    }

    const int p = blockIdx.x;
    const int xcd = p & 7;
    const int s = p >> 3;             // 0..95
    const int mloc = s / 12;          // 0..7
    const int n = s - 12 * mloc;      // 0..11
    const int which = n >> 2;
    const int row0 = (xcd * 8 + mloc) << 7;
    const int col0 = (n & 3) << 7;

    const unsigned short* __restrict__ Bm = Wt + (size_t)which * DIM * DIM;
    const float* __restrict__ bias = (which == 0) ? bq : (which == 1) ? bk : bv;
    unsigned short* __restrict__ obase =
        (which == 0) ? qb : (which == 1) ? kv : kv + DIM;
    const size_t ostride = (which == 0) ? DIM : KV_STRIDE;

    const int lane = tid & 63;
    const int w = tid >> 6;
    const int wm = (w >> 1) * 64;
    const int wn = (w & 1) * 64;
    const int L = lane & 15;
    const int quad = lane >> 4;

    f32x4 zero = {0.f, 0.f, 0.f, 0.f};
    f32x4 acc[4][4];
    #pragma unroll
    for (int i = 0; i < 4; ++i)
        #pragma unroll
        for (int j = 0; j < 4; ++j) acc[i][j] = zero;

    // lane's fragment base: A[row0+wm+i*16+L][quad*8 ...], B[col0+wn+j*16+L][...]
    const unsigned short* __restrict__ ab = xb + (size_t)(row0 + wm + L) * DIM + quad * 8;
    const unsigned short* __restrict__ bb = Bm + (size_t)(col0 + wn + L) * DIM + quad * 8;

    #pragma unroll 2
    for (int k0 = 0; k0 < DIM; k0 += 32) {
        short8 a[4], bfr[4];
        #pragma unroll
        for (int i = 0; i < 4; ++i)
            a[i] = *(const short8*)(const void*)(ab + (size_t)i * 16 * DIM + k0);
        #pragma unroll
        for (int j = 0; j < 4; ++j)
            bfr[j] = *(const short8*)(const void*)(bb + (size_t)j * 16 * DIM + k0);
        #pragma unroll
        for (int i = 0; i < 4; ++i)
            #pragma unroll
            for (int j = 0; j < 4; ++j)
                acc[i][j] = __builtin_amdgcn_mfma_f32_16x16x32_bf16(a[i], bfr[j], acc[i][j], 0, 0, 0);
    }

    // transposed epilogue via LDS: vectorized dwordx4 stores
    float biasv[4];
    #pragma unroll
    for (int j = 0; j < 4; ++j) biasv[j] = bias[col0 + wn + j * 16 + L];

    #pragma unroll
    for (int round = 0; round < 2; ++round) {
        __syncthreads();
        if ((w >> 1) == round) {          // waves whose wm == round*64
            #pragma unroll
            for (int i = 0; i < 4; ++i)
                #pragma unroll
                for (int j = 0; j < 4; ++j)
                    #pragma unroll
                    for (int r = 0; r < 4; ++r)
                        tb[(i * 16 + quad * 4 + r) * 128 + wn + j * 16 + L] =
                            f2bf(acc[i][j][r] + biasv[j]);
        }
        __syncthreads();
        const int rrow = tid >> 2;
        const int seg = (tid & 3) * 32;
        const uint4* srcv = (const uint4*)&tb[rrow * 128 + seg];
        unsigned short* dst =
            obase + (size_t)(row0 + round * 64 + rrow) * ostride + col0 + seg;
        #pragma unroll
        for (int ss = 0; ss < 4; ++ss)
            *(uint4*)(dst + ss * 8) = srcv[ss];
    }
}

// ---------------------------------------------------------------------------
// attention: static wave-per-row (2048 blocks x 4 waves = 8192 waves).
// Fused single pass: w = exp(s*scale) (no max — scores Cauchy-Schwarz
// bounded, no overflow), o += w*v, l += w. k|v interleaved: one 2KB node
// block per edge. Prefix-scan sorted compaction (ascending j, no atomics).
// ---------------------------------------------------------------------------
__device__ __forceinline__ void fused_pass(
    const unsigned short* __restrict__ kv,
    const unsigned short* nbrw, int cn, uint4 qv, int lane,
    float* o, float& l_run)
{
    const float scale = 0.044194173824159220f;   // 1/sqrt(512)
    for (int p0 = 0; p0 < cn; p0 += 4) {
        int j0 = nbrw[p0];
        int j1 = nbrw[(p0 + 1 < cn) ? p0 + 1 : p0];
        int j2 = nbrw[(p0 + 2 < cn) ? p0 + 2 : p0];
        int j3 = nbrw[(p0 + 3 < cn) ? p0 + 3 : p0];
        const unsigned short* n0p = kv + (size_t)j0 * KV_STRIDE + lane * 8;
        const unsigned short* n1p = kv + (size_t)j1 * KV_STRIDE + lane * 8;
        const unsigned short* n2p = kv + (size_t)j2 * KV_STRIDE + lane * 8;
        const unsigned short* n3p = kv + (size_t)j3 * KV_STRIDE + lane * 8;
        uint4 k0v = *(const uint4*)n0p;
        uint4 k1v = *(const uint4*)n1p;
        uint4 k2v = *(const uint4*)n2p;
        uint4 k3v = *(const uint4*)n3p;
        uint4 v0 = *(const uint4*)(n0p + DIM);
        uint4 v1 = *(const uint4*)(n1p + DIM);
        uint4 v2 = *(const uint4*)(n2p + DIM);
        uint4 v3 = *(const uint4*)(n3p + DIM);
        float s0 = wred_sum(dot8(qv, k0v));
        float s1 = wred_sum(dot8(qv, k1v));
        float s2 = wred_sum(dot8(qv, k2v));
        float s3 = wred_sum(dot8(qv, k3v));
        float w0 = __expf(s0 * scale);
        float w1 = (p0 + 1 < cn) ? __expf(s1 * scale) : 0.f;
        float w2 = (p0 + 2 < cn) ? __expf(s2 * scale) : 0.f;
        float w3 = (p0 + 3 < cn) ? __expf(s3 * scale) : 0.f;
        l_run += w0 + w1 + w2 + w3;
        o[0] += w0 * bf_lo(v0.x) + w1 * bf_lo(v1.x) + w2 * bf_lo(v2.x) + w3 * bf_lo(v3.x);
        o[1] += w0 * bf_hi(v0.x) + w1 * bf_hi(v1.x) + w2 * bf_hi(v2.x) + w3 * bf_hi(v3.x);
        o[2] += w0 * bf_lo(v0.y) + w1 * bf_lo(v1.y) + w2 * bf_lo(v2.y) + w3 * bf_lo(v3.y);
        o[3] += w0 * bf_hi(v0.y) + w1 * bf_hi(v1.y) + w2 * bf_hi(v2.y) + w3 * bf_hi(v3.y);
        o[4] += w0 * bf_lo(v0.z) + w1 * bf_lo(v1.z) + w2 * bf_lo(v2.z) + w3 * bf_lo(v3.z);
        o[5] += w0 * bf_hi(v0.z) + w1 * bf_hi(v1.z) + w2 * bf_hi(v2.z) + w3 * bf_hi(v3.z);
        o[6] += w0 * bf_lo(v0.w) + w1 * bf_lo(v1.w) + w2 * bf_lo(v2.w) + w3 * bf_lo(v3.w);
        o[7] += w0 * bf_hi(v0.w) + w1 * bf_hi(v1.w) + w2 * bf_hi(v2.w) + w3 * bf_hi(v3.w);
    }
}

__device__ __forceinline__ int wave_incl_scan(int pc, int lane) {
    int incl = pc;
    #pragma unroll
    for (int off = 1; off <= 32; off <<= 1) {
        int nv = __shfl_up(incl, off, 64);
        if (lane >= off) incl += nv;
    }
    return incl;
}

__global__ __launch_bounds__(256) void attn_kernel(
    const unsigned short* __restrict__ q, const unsigned short* __restrict__ kv,
    const unsigned int* __restrict__ mask, float* __restrict__ out)
{
    __shared__ unsigned short nbr[4][CAPW];   // 4KB total

    const int tid = threadIdx.x;
    const int lane = tid & 63;
    const int wid = tid >> 6;
    const int row = blockIdx.x * 4 + wid;

    const uint4 qv = *(const uint4*)(q + (size_t)row * DIM + lane * 8);
    const unsigned int* __restrict__ mrow = mask + (size_t)row * MASK_WORDS;

    const uint4 mv = ((const uint4*)mrow)[lane];
    unsigned int wds[4] = {mv.x, mv.y, mv.z, mv.w};
    int pc = __popc(wds[0]) + __popc(wds[1]) + __popc(wds[2]) + __popc(wds[3]);
    const int total = wred_sumi(pc);

    float o[8];
    #pragma unroll
    for (int i = 0; i < 8; ++i) o[i] = 0.f;

    if (total == 0) {
        // all-NEG row -> uniform 1/N over all v rows (prob ~0, exactness only)
        for (int j = 0; j < N_NODES; ++j) {
            uint4 vv = *(const uint4*)(kv + (size_t)j * KV_STRIDE + DIM + lane * 8);
            o[0] += bf_lo(vv.x); o[1] += bf_hi(vv.x);
            o[2] += bf_lo(vv.y); o[3] += bf_hi(vv.y);
            o[4] += bf_lo(vv.z); o[5] += bf_hi(vv.z);
            o[6] += bf_lo(vv.w); o[7] += bf_hi(vv.w);
        }
        const float sc = 1.0f / N_NODES;
        float4 r0 = {o[0] * sc, o[1] * sc, o[2] * sc, o[3] * sc};
        float4 r1 = {o[4] * sc, o[5] * sc, o[6] * sc, o[7] * sc};
        *(float4*)(out + (size_t)row * DIM + lane * 8) = r0;
        *(float4*)(out + (size_t)row * DIM + lane * 8 + 4) = r1;
        return;
    }

    float l_run = 0.f;

    if (total <= CAPW) {
        // single chunk: prefix-scan compaction, ascending neighbor ids
        int pos = wave_incl_scan(pc, lane) - pc;
        #pragma unroll
        for (int t = 0; t < 4; ++t) {
            unsigned int ww = wds[t];
            int base = (lane * 4 + t) * 32;
            while (ww) {
                int b = __ffs(ww) - 1; ww &= ww - 1;
                nbr[wid][pos++] = (unsigned short)(base + b);
            }
        }
        fused_pass(kv, nbr[wid], total, qv, lane, o, l_run);
    } else {
        // 16 chunks of 16 words (<=512 bits each) — exact for any degree
        for (int c = 0; c < 16; ++c) {
            unsigned int ww = 0;
            if (lane < 16) ww = mrow[c * 16 + lane];
            int pcc = __popc(ww);
            int incl = wave_incl_scan(pcc, lane);
            int cn = __shfl(incl, 63, 64);
            if (cn == 0) continue;
            int pos = incl - pcc;
            int base = (c * 16 + lane) * 32;
            while (ww) {
                int b = __ffs(ww) - 1; ww &= ww - 1;
                nbr[wid][pos++] = (unsigned short)(base + b);
            }
            fused_pass(kv, nbr[wid], cn, qv, lane, o, l_run);
        }
    }

    const float inv = 1.0f / l_run;
    float4 r0 = {o[0] * inv, o[1] * inv, o[2] * inv, o[3] * inv};
    float4 r1 = {o[4] * inv, o[5] * inv, o[6] * inv, o[7] * inv};
    *(float4*)(out + (size_t)row * DIM + lane * 8) = r0;
    *(float4*)(out + (size_t)row * DIM + lane * 8 + 4) = r1;
}

// ---------------------------------------------------------------------------
extern "C" void kernel_launch(void* const* d_in, const int* in_sizes, int n_in,
                              void* d_out, int out_size, void* d_ws, size_t ws_size,
                              hipStream_t stream)
{
    const float* x  = (const float*)d_in[0];
    const int*   ei = (const int*)d_in[1];
    const float* Wq = (const float*)d_in[2];
    const float* bq = (const float*)d_in[3];
    const float* Wk = (const float*)d_in[4];
    const float* bk = (const float*)d_in[5];
    const float* Wv = (const float*)d_in[6];
    const float* bv = (const float*)d_in[7];
    float* out = (float*)d_out;

    const int E = in_sizes[1] / 2;
    const size_t NM = (size_t)N_NODES * DIM;

    // ws: xb (8MB) | Wt (1.5MB) | qb (8MB) | kv interleaved (16MB) | mask (8MB)
    unsigned short* xb = (unsigned short*)d_ws;
    unsigned short* Wt = xb + NM;
    unsigned short* qb = Wt + (size_t)3 * DIM * DIM;
    unsigned short* kv = qb + NM;
    unsigned int* mask = (unsigned int*)(kv + (size_t)N_NODES * KV_STRIDE);

    prep1<<<4864, 256, 0, stream>>>(x, xb, Wq, Wk, Wv, Wt, mask);

    gemm_scatter<<<768 + (E + 255) / 256, 256, 0, stream>>>(
        xb, Wt, bq, bk, bv, qb, kv, ei, mask, E);

    attn_kernel<<<N_NODES / 4, 256, 0, stream>>>(qb, kv, mask, out);
}

// Round 8
// 172.232 us; speedup vs baseline: 1.1757x; 1.1757x over previous
//
#include <hip/hip_runtime.h>

// N=8192 nodes, D=512, E=262144. NEG=-1e6 => exp underflows to exactly 0,
// so softmax is EXACTLY sparse over each row's neighbor set (bitmask dedupes
// duplicate edges, matching .at[].set(1.0) idempotence).
//
// R8: gemm back to LDS + global_load_lds 2-barrier K-loop (R4 skeleton,
//     known-good) but BK=64 -> 8 iterations (half the barrier drains, 32
//     MFMA/wave per barrier). XCD swizzle kept (R7 proved FETCH=17MB).
//     kv stays interleaved; scatter merged into gemm launch; attn = R6 fused
//     single-pass wave-per-row.

#define N_NODES 8192
#define DIM 512
#define MASK_WORDS 256   // 8192 bits / 32
#define CAPW 512         // per-wave neighbor chunk capacity
#define KV_STRIDE 1024   // ushorts per node in interleaved k|v buffer

typedef __attribute__((ext_vector_type(8))) short short8;
typedef __attribute__((ext_vector_type(4))) float f32x4;

__device__ __forceinline__ unsigned short f2bf(float f) {
    unsigned int u = __float_as_uint(f);
    u += 0x7fffu + ((u >> 16) & 1u);          // round-to-nearest-even
    return (unsigned short)(u >> 16);
}
__device__ __forceinline__ float bf_lo(unsigned int w) { return __uint_as_float(w << 16); }
__device__ __forceinline__ float bf_hi(unsigned int w) { return __uint_as_float(w & 0xffff0000u); }

__device__ __forceinline__ float wred_sum(float s) {
    #pragma unroll
    for (int off = 1; off <= 32; off <<= 1) s += __shfl_xor(s, off, 64);
    return s;
}
__device__ __forceinline__ int wred_sumi(int s) {
    #pragma unroll
    for (int off = 1; off <= 32; off <<= 1) s += __shfl_xor(s, off, 64);
    return s;
}
__device__ __forceinline__ float dot8(uint4 a, uint4 b) {
    return bf_lo(a.x) * bf_lo(b.x) + bf_hi(a.x) * bf_hi(b.x)
         + bf_lo(a.y) * bf_lo(b.y) + bf_hi(a.y) * bf_hi(b.y)
         + bf_lo(a.z) * bf_lo(b.z) + bf_hi(a.z) * bf_hi(b.z)
         + bf_lo(a.w) * bf_lo(b.w) + bf_hi(a.w) * bf_hi(b.w);
}

// ---------------------------------------------------------------------------
// prep1: [0,4096) convert x -> bf16 AND zero 2KB of mask each |
//        [4096,4864) transpose-convert W -> Wt
// ---------------------------------------------------------------------------
__global__ __launch_bounds__(256) void prep1(
    const float* __restrict__ x, unsigned short* __restrict__ xb,
    const float* __restrict__ Wq, const float* __restrict__ Wk,
    const float* __restrict__ Wv, unsigned short* __restrict__ Wt,
    unsigned int* __restrict__ mask)
{
    __shared__ float sm[32][33];
    const int b = blockIdx.x;
    if (b < 4096) {
        int i = b * 256 + threadIdx.x;
        float4 f = ((const float4*)x)[i];
        ushort4 o;
        o.x = f2bf(f.x); o.y = f2bf(f.y); o.z = f2bf(f.z); o.w = f2bf(f.w);
        ((ushort4*)xb)[i] = o;
        ((uint2*)mask)[i] = make_uint2(0u, 0u);     // 4096*256*8B = 8MB
    } else {
        int bb = b - 4096;
        int which = bb >> 8, t = bb & 255;
        const float* __restrict__ W = (which == 0) ? Wq : (which == 1) ? Wk : Wv;
        unsigned short* __restrict__ outp = Wt + (size_t)which * DIM * DIM;
        int n0 = (t & 15) * 32, k0 = (t >> 4) * 32;
        int tx = threadIdx.x & 31, ty = threadIdx.x >> 5;
        #pragma unroll
        for (int r = 0; r < 4; ++r)
            sm[ty + 8 * r][tx] = W[(size_t)(k0 + ty + 8 * r) * DIM + n0 + tx];
        __syncthreads();
        #pragma unroll
        for (int r = 0; r < 4; ++r)
            outp[(size_t)(n0 + ty + 8 * r) * DIM + k0 + tx] = f2bf(sm[tx][ty + 8 * r]);
    }
}

// ---------------------------------------------------------------------------
// gemm + edge scatter in one launch.
// blocks [0,768): bf16 MFMA GEMM, 128x128 tile, BK=64, global_load_lds
//   width-16 staging, 2-barrier K-loop (8 iters). XCD swizzle keeps per-XCD
//   A slice (1MB) + B (1.5MB) L2-resident. q stride 512; k,v interleaved
//   per node at stride 1024.
// blocks [768,...): scatter edges into bitmask.
// ---------------------------------------------------------------------------
__device__ __forceinline__ void load_lds16(const unsigned short* g, unsigned short* l) {
    __builtin_amdgcn_global_load_lds(
        (const __attribute__((address_space(1))) unsigned int*)g,
        (__attribute__((address_space(3))) unsigned int*)l, 16, 0, 0);
}

__global__ __launch_bounds__(256) void gemm_scatter(
    const unsigned short* __restrict__ xb, const unsigned short* __restrict__ Wt,
    const float* __restrict__ bq, const float* __restrict__ bk, const float* __restrict__ bv,
    unsigned short* __restrict__ qb, unsigned short* __restrict__ kv,
    const int* __restrict__ ei, unsigned int* __restrict__ mask, int E)
{
    const int tid = threadIdx.x;

    if (blockIdx.x >= 768) {
        int e = (blockIdx.x - 768) * 256 + tid;
        if (e < E) {
            int src = ei[e];
            int dst = ei[E + e];
            atomicOr(&mask[(size_t)src * MASK_WORDS + (dst >> 5)], 1u << (dst & 31));
        }
        return;
    }

    const int p = blockIdx.x;
    const int xcd = p & 7;
    const int s = p >> 3;             // 0..95
    const int mloc = s / 12;          // 0..7
    const int n = s - 12 * mloc;      // 0..11
    const int which = n >> 2;
    const int row0 = (xcd * 8 + mloc) << 7;
    const int col0 = (n & 3) << 7;

    const unsigned short* __restrict__ Bm = Wt + (size_t)which * DIM * DIM;
    const float* __restrict__ bias = (which == 0) ? bq : (which == 1) ? bk : bv;
    unsigned short* __restrict__ obase =
        (which == 0) ? qb : (which == 1) ? kv : kv + DIM;
    const size_t ostride = (which == 0) ? DIM : KV_STRIDE;

    const int lane = tid & 63;
    const int w = tid >> 6;
    const int wm = (w >> 1) * 64;
    const int wn = (w & 1) * 64;
    const int L = lane & 15;
    const int quad = lane >> 4;

    __shared__ unsigned short As[128 * 64];   // 16KB, row stride 64 us (128B)
    __shared__ unsigned short Bs[128 * 64];   // 16KB

    f32x4 zero = {0.f, 0.f, 0.f, 0.f};
    f32x4 acc[4][4];
    #pragma unroll
    for (int i = 0; i < 4; ++i)
        #pragma unroll
        for (int j = 0; j < 4; ++j) acc[i][j] = zero;

    // staging: 1024 chunks of 16B per matrix per iter; chunk c = m*8+g holds
    // [row m][k0 + g*8 .. +8). Thread covers c = tid + t*256, t=0..3.
    int sm_[4], sg_[4];
    #pragma unroll
    for (int t = 0; t < 4; ++t) {
        int c = tid + t * 256;
        sm_[t] = c >> 3;
        sg_[t] = (c & 7) << 3;
    }
    const unsigned short* __restrict__ arow = xb + (size_t)row0 * DIM;
    const unsigned short* __restrict__ brow = Bm + (size_t)col0 * DIM;

    for (int k0 = 0; k0 < DIM; k0 += 64) {
        #pragma unroll
        for (int t = 0; t < 4; ++t)
            load_lds16(arow + (size_t)sm_[t] * DIM + k0 + sg_[t], As + (tid + t * 256) * 8);
        #pragma unroll
        for (int t = 0; t < 4; ++t)
            load_lds16(brow + (size_t)sm_[t] * DIM + k0 + sg_[t], Bs + (tid + t * 256) * 8);
        __syncthreads();    // compiler emits vmcnt(0) drain before s_barrier

        short8 a[2][4], bfr[2][4];
        #pragma unroll
        for (int kk = 0; kk < 2; ++kk) {
            #pragma unroll
            for (int i = 0; i < 4; ++i)
                a[kk][i] = *(const short8*)(const void*)
                    &As[(wm + i * 16 + L) * 64 + kk * 32 + quad * 8];
            #pragma unroll
            for (int j = 0; j < 4; ++j)
                bfr[kk][j] = *(const short8*)(const void*)
                    &Bs[(wn + j * 16 + L) * 64 + kk * 32 + quad * 8];
        }
        #pragma unroll
        for (int kk = 0; kk < 2; ++kk)
            #pragma unroll
            for (int i = 0; i < 4; ++i)
                #pragma unroll
                for (int j = 0; j < 4; ++j)
                    acc[i][j] = __builtin_amdgcn_mfma_f32_16x16x32_bf16(
                        a[kk][i], bfr[kk][j], acc[i][j], 0, 0, 0);
        __syncthreads();
    }

    // plain epilogue (C/D layout: col = L, row = quad*4 + r)
    float biasv[4];
    #pragma unroll
    for (int j = 0; j < 4; ++j) biasv[j] = bias[col0 + wn + j * 16 + L];
    #pragma unroll
    for (int i = 0; i < 4; ++i) {
        int r0 = row0 + wm + i * 16 + quad * 4;
        #pragma unroll
        for (int j = 0; j < 4; ++j) {
            int c = col0 + wn + j * 16 + L;
            #pragma unroll
            for (int r = 0; r < 4; ++r)
                obase[(size_t)(r0 + r) * ostride + c] = f2bf(acc[i][j][r] + biasv[j]);
        }
    }
}

// ---------------------------------------------------------------------------
// attention: static wave-per-row (2048 blocks x 4 waves = 8192 waves).
// Fused single pass: w = exp(s*scale) (no max — scores Cauchy-Schwarz
// bounded, no overflow), o += w*v, l += w. k|v interleaved: one 2KB node
// block per edge. Prefix-scan sorted compaction (ascending j, no atomics).
// ---------------------------------------------------------------------------
__device__ __forceinline__ void fused_pass(
    const unsigned short* __restrict__ kv,
    const unsigned short* nbrw, int cn, uint4 qv, int lane,
    float* o, float& l_run)
{
    const float scale = 0.044194173824159220f;   // 1/sqrt(512)
    for (int p0 = 0; p0 < cn; p0 += 4) {
        int j0 = nbrw[p0];
        int j1 = nbrw[(p0 + 1 < cn) ? p0 + 1 : p0];
        int j2 = nbrw[(p0 + 2 < cn) ? p0 + 2 : p0];
        int j3 = nbrw[(p0 + 3 < cn) ? p0 + 3 : p0];
        const unsigned short* n0p = kv + (size_t)j0 * KV_STRIDE + lane * 8;
        const unsigned short* n1p = kv + (size_t)j1 * KV_STRIDE + lane * 8;
        const unsigned short* n2p = kv + (size_t)j2 * KV_STRIDE + lane * 8;
        const unsigned short* n3p = kv + (size_t)j3 * KV_STRIDE + lane * 8;
        uint4 k0v = *(const uint4*)n0p;
        uint4 k1v = *(const uint4*)n1p;
        uint4 k2v = *(const uint4*)n2p;
        uint4 k3v = *(const uint4*)n3p;
        uint4 v0 = *(const uint4*)(n0p + DIM);
        uint4 v1 = *(const uint4*)(n1p + DIM);
        uint4 v2 = *(const uint4*)(n2p + DIM);
        uint4 v3 = *(const uint4*)(n3p + DIM);
        float s0 = wred_sum(dot8(qv, k0v));
        float s1 = wred_sum(dot8(qv, k1v));
        float s2 = wred_sum(dot8(qv, k2v));
        float s3 = wred_sum(dot8(qv, k3v));
        float w0 = __expf(s0 * scale);
        float w1 = (p0 + 1 < cn) ? __expf(s1 * scale) : 0.f;
        float w2 = (p0 + 2 < cn) ? __expf(s2 * scale) : 0.f;
        float w3 = (p0 + 3 < cn) ? __expf(s3 * scale) : 0.f;
        l_run += w0 + w1 + w2 + w3;
        o[0] += w0 * bf_lo(v0.x) + w1 * bf_lo(v1.x) + w2 * bf_lo(v2.x) + w3 * bf_lo(v3.x);
        o[1] += w0 * bf_hi(v0.x) + w1 * bf_hi(v1.x) + w2 * bf_hi(v2.x) + w3 * bf_hi(v3.x);
        o[2] += w0 * bf_lo(v0.y) + w1 * bf_lo(v1.y) + w2 * bf_lo(v2.y) + w3 * bf_lo(v3.y);
        o[3] += w0 * bf_hi(v0.y) + w1 * bf_hi(v1.y) + w2 * bf_hi(v2.y) + w3 * bf_hi(v3.y);
        o[4] += w0 * bf_lo(v0.z) + w1 * bf_lo(v1.z) + w2 * bf_lo(v2.z) + w3 * bf_lo(v3.z);
        o[5] += w0 * bf_hi(v0.z) + w1 * bf_hi(v1.z) + w2 * bf_hi(v2.z) + w3 * bf_hi(v3.z);
        o[6] += w0 * bf_lo(v0.w) + w1 * bf_lo(v1.w) + w2 * bf_lo(v2.w) + w3 * bf_lo(v3.w);
        o[7] += w0 * bf_hi(v0.w) + w1 * bf_hi(v1.w) + w2 * bf_hi(v2.w) + w3 * bf_hi(v3.w);
    }
}

__device__ __forceinline__ int wave_incl_scan(int pc, int lane) {
    int incl = pc;
    #pragma unroll
    for (int off = 1; off <= 32; off <<= 1) {
        int nv = __shfl_up(incl, off, 64);
        if (lane >= off) incl += nv;
    }
    return incl;
}

__global__ __launch_bounds__(256) void attn_kernel(
    const unsigned short* __restrict__ q, const unsigned short* __restrict__ kv,
    const unsigned int* __restrict__ mask, float* __restrict__ out)
{
    __shared__ unsigned short nbr[4][CAPW];   // 4KB total

    const int tid = threadIdx.x;
    const int lane = tid & 63;
    const int wid = tid >> 6;
    const int row = blockIdx.x * 4 + wid;

    const uint4 qv = *(const uint4*)(q + (size_t)row * DIM + lane * 8);
    const unsigned int* __restrict__ mrow = mask + (size_t)row * MASK_WORDS;

    const uint4 mv = ((const uint4*)mrow)[lane];
    unsigned int wds[4] = {mv.x, mv.y, mv.z, mv.w};
    int pc = __popc(wds[0]) + __popc(wds[1]) + __popc(wds[2]) + __popc(wds[3]);
    const int total = wred_sumi(pc);

    float o[8];
    #pragma unroll
    for (int i = 0; i < 8; ++i) o[i] = 0.f;

    if (total == 0) {
        // all-NEG row -> uniform 1/N over all v rows (prob ~0, exactness only)
        for (int j = 0; j < N_NODES; ++j) {
            uint4 vv = *(const uint4*)(kv + (size_t)j * KV_STRIDE + DIM + lane * 8);
            o[0] += bf_lo(vv.x); o[1] += bf_hi(vv.x);
            o[2] += bf_lo(vv.y); o[3] += bf_hi(vv.y);
            o[4] += bf_lo(vv.z); o[5] += bf_hi(vv.z);
            o[6] += bf_lo(vv.w); o[7] += bf_hi(vv.w);
        }
        const float sc = 1.0f / N_NODES;
        float4 r0 = {o[0] * sc, o[1] * sc, o[2] * sc, o[3] * sc};
        float4 r1 = {o[4] * sc, o[5] * sc, o[6] * sc, o[7] * sc};
        *(float4*)(out + (size_t)row * DIM + lane * 8) = r0;
        *(float4*)(out + (size_t)row * DIM + lane * 8 + 4) = r1;
        return;
    }

    float l_run = 0.f;

    if (total <= CAPW) {
        // single chunk: prefix-scan compaction, ascending neighbor ids
        int pos = wave_incl_scan(pc, lane) - pc;
        #pragma unroll
        for (int t = 0; t < 4; ++t) {
            unsigned int ww = wds[t];
            int base = (lane * 4 + t) * 32;
            while (ww) {
                int b = __ffs(ww) - 1; ww &= ww - 1;
                nbr[wid][pos++] = (unsigned short)(base + b);
            }
        }
        fused_pass(kv, nbr[wid], total, qv, lane, o, l_run);
    } else {
        // 16 chunks of 16 words (<=512 bits each) — exact for any degree
        for (int c = 0; c < 16; ++c) {
            unsigned int ww = 0;
            if (lane < 16) ww = mrow[c * 16 + lane];
            int pcc = __popc(ww);
            int incl = wave_incl_scan(pcc, lane);
            int cn = __shfl(incl, 63, 64);
            if (cn == 0) continue;
            int pos = incl - pcc;
            int base = (c * 16 + lane) * 32;
            while (ww) {
                int b = __ffs(ww) - 1; ww &= ww - 1;
                nbr[wid][pos++] = (unsigned short)(base + b);
            }
            fused_pass(kv, nbr[wid], cn, qv, lane, o, l_run);
        }
    }

    const float inv = 1.0f / l_run;
    float4 r0 = {o[0] * inv, o[1] * inv, o[2] * inv, o[3] * inv};
    float4 r1 = {o[4] * inv, o[5] * inv, o[6] * inv, o[7] * inv};
    *(float4*)(out + (size_t)row * DIM + lane * 8) = r0;
    *(float4*)(out + (size_t)row * DIM + lane * 8 + 4) = r1;
}

// ---------------------------------------------------------------------------
extern "C" void kernel_launch(void* const* d_in, const int* in_sizes, int n_in,
                              void* d_out, int out_size, void* d_ws, size_t ws_size,
                              hipStream_t stream)
{
    const float* x  = (const float*)d_in[0];
    const int*   ei = (const int*)d_in[1];
    const float* Wq = (const float*)d_in[2];
    const float* bq = (const float*)d_in[3];
    const float* Wk = (const float*)d_in[4];
    const float* bk = (const float*)d_in[5];
    const float* Wv = (const float*)d_in[6];
    const float* bv = (const float*)d_in[7];
    float* out = (float*)d_out;

    const int E = in_sizes[1] / 2;
    const size_t NM = (size_t)N_NODES * DIM;

    // ws: xb (8MB) | Wt (1.5MB) | qb (8MB) | kv interleaved (16MB) | mask (8MB)
    unsigned short* xb = (unsigned short*)d_ws;
    unsigned short* Wt = xb + NM;
    unsigned short* qb = Wt + (size_t)3 * DIM * DIM;
    unsigned short* kv = qb + NM;
    unsigned int* mask = (unsigned int*)(kv + (size_t)N_NODES * KV_STRIDE);

    prep1<<<4864, 256, 0, stream>>>(x, xb, Wq, Wk, Wv, Wt, mask);

    gemm_scatter<<<768 + (E + 255) / 256, 256, 0, stream>>>(
        xb, Wt, bq, bk, bv, qb, kv, ei, mask, E);

    attn_kernel<<<N_NODES / 4, 256, 0, stream>>>(qb, kv, mask, out);
}

// Round 9
// 166.175 us; speedup vs baseline: 1.2186x; 1.0365x over previous
//
#include <hip/hip_runtime.h>

// N=8192 nodes, D=512, E=262144. NEG=-1e6 => exp underflows to exactly 0,
// so softmax is EXACTLY sparse over each row's neighbor set (bitmask dedupes
// duplicate edges, matching .at[].set(1.0) idempotence).
//
// R9: attn gains COLUMN PHASING — each wave walks its neighbors in 4
//     ascending node-range phases (2048 nodes = 4MB kv slice = one XCD L2).
//     Concurrent waves stay loosely phase-aligned, so the hot kv slice is
//     L2-resident; no-max exp makes cross-phase merge a plain add.
//     gemm = R8 (BK=64, global_load_lds, XCD swizzle); scatter merged in.

#define N_NODES 8192
#define DIM 512
#define MASK_WORDS 256   // 8192 bits / 32
#define PCAP 2048        // per-wave per-phase neighbor capacity (bulletproof)
#define KV_STRIDE 1024   // ushorts per node in interleaved k|v buffer

typedef __attribute__((ext_vector_type(8))) short short8;
typedef __attribute__((ext_vector_type(4))) float f32x4;

__device__ __forceinline__ unsigned short f2bf(float f) {
    unsigned int u = __float_as_uint(f);
    u += 0x7fffu + ((u >> 16) & 1u);          // round-to-nearest-even
    return (unsigned short)(u >> 16);
}
__device__ __forceinline__ float bf_lo(unsigned int w) { return __uint_as_float(w << 16); }
__device__ __forceinline__ float bf_hi(unsigned int w) { return __uint_as_float(w & 0xffff0000u); }

__device__ __forceinline__ float wred_sum(float s) {
    #pragma unroll
    for (int off = 1; off <= 32; off <<= 1) s += __shfl_xor(s, off, 64);
    return s;
}
__device__ __forceinline__ float dot8(uint4 a, uint4 b) {
    return bf_lo(a.x) * bf_lo(b.x) + bf_hi(a.x) * bf_hi(b.x)
         + bf_lo(a.y) * bf_lo(b.y) + bf_hi(a.y) * bf_hi(b.y)
         + bf_lo(a.z) * bf_lo(b.z) + bf_hi(a.z) * bf_hi(b.z)
         + bf_lo(a.w) * bf_lo(b.w) + bf_hi(a.w) * bf_hi(b.w);
}
__device__ __forceinline__ int wave_incl_scan(int pc, int lane) {
    int incl = pc;
    #pragma unroll
    for (int off = 1; off <= 32; off <<= 1) {
        int nv = __shfl_up(incl, off, 64);
        if (lane >= off) incl += nv;
    }
    return incl;
}

// ---------------------------------------------------------------------------
// prep1: [0,4096) convert x -> bf16 AND zero 2KB of mask each |
//        [4096,4864) transpose-convert W -> Wt
// ---------------------------------------------------------------------------
__global__ __launch_bounds__(256) void prep1(
    const float* __restrict__ x, unsigned short* __restrict__ xb,
    const float* __restrict__ Wq, const float* __restrict__ Wk,
    const float* __restrict__ Wv, unsigned short* __restrict__ Wt,
    unsigned int* __restrict__ mask)
{
    __shared__ float sm[32][33];
    const int b = blockIdx.x;
    if (b < 4096) {
        int i = b * 256 + threadIdx.x;
        float4 f = ((const float4*)x)[i];
        ushort4 o;
        o.x = f2bf(f.x); o.y = f2bf(f.y); o.z = f2bf(f.z); o.w = f2bf(f.w);
        ((ushort4*)xb)[i] = o;
        ((uint2*)mask)[i] = make_uint2(0u, 0u);     // 4096*256*8B = 8MB
    } else {
        int bb = b - 4096;
        int which = bb >> 8, t = bb & 255;
        const float* __restrict__ W = (which == 0) ? Wq : (which == 1) ? Wk : Wv;
        unsigned short* __restrict__ outp = Wt + (size_t)which * DIM * DIM;
        int n0 = (t & 15) * 32, k0 = (t >> 4) * 32;
        int tx = threadIdx.x & 31, ty = threadIdx.x >> 5;
        #pragma unroll
        for (int r = 0; r < 4; ++r)
            sm[ty + 8 * r][tx] = W[(size_t)(k0 + ty + 8 * r) * DIM + n0 + tx];
        __syncthreads();
        #pragma unroll
        for (int r = 0; r < 4; ++r)
            outp[(size_t)(n0 + ty + 8 * r) * DIM + k0 + tx] = f2bf(sm[tx][ty + 8 * r]);
    }
}

// ---------------------------------------------------------------------------
// gemm + edge scatter in one launch (R8 skeleton).
// blocks [0,768): bf16 MFMA GEMM, 128x128 tile, BK=64, global_load_lds
//   width-16 staging, 2-barrier K-loop (8 iters). XCD swizzle keeps per-XCD
//   A slice (1MB) + B (1.5MB) L2-resident. q stride 512; k,v interleaved
//   per node at stride 1024.
// blocks [768,...): scatter edges into bitmask.
// ---------------------------------------------------------------------------
__device__ __forceinline__ void load_lds16(const unsigned short* g, unsigned short* l) {
    __builtin_amdgcn_global_load_lds(
        (const __attribute__((address_space(1))) unsigned int*)g,
        (__attribute__((address_space(3))) unsigned int*)l, 16, 0, 0);
}

__global__ __launch_bounds__(256) void gemm_scatter(
    const unsigned short* __restrict__ xb, const unsigned short* __restrict__ Wt,
    const float* __restrict__ bq, const float* __restrict__ bk, const float* __restrict__ bv,
    unsigned short* __restrict__ qb, unsigned short* __restrict__ kv,
    const int* __restrict__ ei, unsigned int* __restrict__ mask, int E)
{
    const int tid = threadIdx.x;

    if (blockIdx.x >= 768) {
        int e = (blockIdx.x - 768) * 256 + tid;
        if (e < E) {
            int src = ei[e];
            int dst = ei[E + e];
            atomicOr(&mask[(size_t)src * MASK_WORDS + (dst >> 5)], 1u << (dst & 31));
        }
        return;
    }

    const int p = blockIdx.x;
    const int xcd = p & 7;
    const int s = p >> 3;             // 0..95
    const int mloc = s / 12;          // 0..7
    const int n = s - 12 * mloc;      // 0..11
    const int which = n >> 2;
    const int row0 = (xcd * 8 + mloc) << 7;
    const int col0 = (n & 3) << 7;

    const unsigned short* __restrict__ Bm = Wt + (size_t)which * DIM * DIM;
    const float* __restrict__ bias = (which == 0) ? bq : (which == 1) ? bk : bv;
    unsigned short* __restrict__ obase =
        (which == 0) ? qb : (which == 1) ? kv : kv + DIM;
    const size_t ostride = (which == 0) ? DIM : KV_STRIDE;

    const int lane = tid & 63;
    const int w = tid >> 6;
    const int wm = (w >> 1) * 64;
    const int wn = (w & 1) * 64;
    const int L = lane & 15;
    const int quad = lane >> 4;

    __shared__ unsigned short As[128 * 64];   // 16KB, row stride 64 us (128B)
    __shared__ unsigned short Bs[128 * 64];   // 16KB

    f32x4 zero = {0.f, 0.f, 0.f, 0.f};
    f32x4 acc[4][4];
    #pragma unroll
    for (int i = 0; i < 4; ++i)
        #pragma unroll
        for (int j = 0; j < 4; ++j) acc[i][j] = zero;

    // staging: 1024 chunks of 16B per matrix per iter; chunk c = m*8+g holds
    // [row m][k0 + g*8 .. +8). Thread covers c = tid + t*256, t=0..3.
    int sm_[4], sg_[4];
    #pragma unroll
    for (int t = 0; t < 4; ++t) {
        int c = tid + t * 256;
        sm_[t] = c >> 3;
        sg_[t] = (c & 7) << 3;
    }
    const unsigned short* __restrict__ arow = xb + (size_t)row0 * DIM;
    const unsigned short* __restrict__ brow = Bm + (size_t)col0 * DIM;

    for (int k0 = 0; k0 < DIM; k0 += 64) {
        #pragma unroll
        for (int t = 0; t < 4; ++t)
            load_lds16(arow + (size_t)sm_[t] * DIM + k0 + sg_[t], As + (tid + t * 256) * 8);
        #pragma unroll
        for (int t = 0; t < 4; ++t)
            load_lds16(brow + (size_t)sm_[t] * DIM + k0 + sg_[t], Bs + (tid + t * 256) * 8);
        __syncthreads();

        short8 a[2][4], bfr[2][4];
        #pragma unroll
        for (int kk = 0; kk < 2; ++kk) {
            #pragma unroll
            for (int i = 0; i < 4; ++i)
                a[kk][i] = *(const short8*)(const void*)
                    &As[(wm + i * 16 + L) * 64 + kk * 32 + quad * 8];
            #pragma unroll
            for (int j = 0; j < 4; ++j)
                bfr[kk][j] = *(const short8*)(const void*)
                    &Bs[(wn + j * 16 + L) * 64 + kk * 32 + quad * 8];
        }
        #pragma unroll
        for (int kk = 0; kk < 2; ++kk)
            #pragma unroll
            for (int i = 0; i < 4; ++i)
                #pragma unroll
                for (int j = 0; j < 4; ++j)
                    acc[i][j] = __builtin_amdgcn_mfma_f32_16x16x32_bf16(
                        a[kk][i], bfr[kk][j], acc[i][j], 0, 0, 0);
        __syncthreads();
    }

    // plain epilogue (C/D layout: col = L, row = quad*4 + r)
    float biasv[4];
    #pragma unroll
    for (int j = 0; j < 4; ++j) biasv[j] = bias[col0 + wn + j * 16 + L];
    #pragma unroll
    for (int i = 0; i < 4; ++i) {
        int r0 = row0 + wm + i * 16 + quad * 4;
        #pragma unroll
        for (int j = 0; j < 4; ++j) {
            int c = col0 + wn + j * 16 + L;
            #pragma unroll
            for (int r = 0; r < 4; ++r)
                obase[(size_t)(r0 + r) * ostride + c] = f2bf(acc[i][j][r] + biasv[j]);
        }
    }
}

// ---------------------------------------------------------------------------
// attention: static wave-per-row (2048 blocks x 4 waves = 8192 waves),
// COLUMN-PHASED: 4 phases over ascending node ranges of 2048 (mask words
// [ph*64, ph*64+64), one per lane). The hot kv slice per phase is 4MB =
// one XCD L2. No-max exp (scores Cauchy-Schwarz bounded) => phases merge
// by plain accumulation of o and l. Prefix-scan compaction, no atomics.
// ---------------------------------------------------------------------------
__device__ __forceinline__ void fused_pass(
    const unsigned short* __restrict__ kv,
    const unsigned short* nbrw, int cn, uint4 qv, int lane,
    float* o, float& l_run)
{
    const float scale = 0.044194173824159220f;   // 1/sqrt(512)
    for (int p0 = 0; p0 < cn; p0 += 4) {
        int j0 = nbrw[p0];
        int j1 = nbrw[(p0 + 1 < cn) ? p0 + 1 : p0];
        int j2 = nbrw[(p0 + 2 < cn) ? p0 + 2 : p0];
        int j3 = nbrw[(p0 + 3 < cn) ? p0 + 3 : p0];
        const unsigned short* n0p = kv + (size_t)j0 * KV_STRIDE + lane * 8;
        const unsigned short* n1p = kv + (size_t)j1 * KV_STRIDE + lane * 8;
        const unsigned short* n2p = kv + (size_t)j2 * KV_STRIDE + lane * 8;
        const unsigned short* n3p = kv + (size_t)j3 * KV_STRIDE + lane * 8;
        uint4 k0v = *(const uint4*)n0p;
        uint4 k1v = *(const uint4*)n1p;
        uint4 k2v = *(const uint4*)n2p;
        uint4 k3v = *(const uint4*)n3p;
        uint4 v0 = *(const uint4*)(n0p + DIM);
        uint4 v1 = *(const uint4*)(n1p + DIM);
        uint4 v2 = *(const uint4*)(n2p + DIM);
        uint4 v3 = *(const uint4*)(n3p + DIM);
        float s0 = wred_sum(dot8(qv, k0v));
        float s1 = wred_sum(dot8(qv, k1v));
        float s2 = wred_sum(dot8(qv, k2v));
        float s3 = wred_sum(dot8(qv, k3v));
        float w0 = __expf(s0 * scale);
        float w1 = (p0 + 1 < cn) ? __expf(s1 * scale) : 0.f;
        float w2 = (p0 + 2 < cn) ? __expf(s2 * scale) : 0.f;
        float w3 = (p0 + 3 < cn) ? __expf(s3 * scale) : 0.f;
        l_run += w0 + w1 + w2 + w3;
        o[0] += w0 * bf_lo(v0.x) + w1 * bf_lo(v1.x) + w2 * bf_lo(v2.x) + w3 * bf_lo(v3.x);
        o[1] += w0 * bf_hi(v0.x) + w1 * bf_hi(v1.x) + w2 * bf_hi(v2.x) + w3 * bf_hi(v3.x);
        o[2] += w0 * bf_lo(v0.y) + w1 * bf_lo(v1.y) + w2 * bf_lo(v2.y) + w3 * bf_lo(v3.y);
        o[3] += w0 * bf_hi(v0.y) + w1 * bf_hi(v1.y) + w2 * bf_hi(v2.y) + w3 * bf_hi(v3.y);
        o[4] += w0 * bf_lo(v0.z) + w1 * bf_lo(v1.z) + w2 * bf_lo(v2.z) + w3 * bf_lo(v3.z);
        o[5] += w0 * bf_hi(v0.z) + w1 * bf_hi(v1.z) + w2 * bf_hi(v2.z) + w3 * bf_hi(v3.z);
        o[6] += w0 * bf_lo(v0.w) + w1 * bf_lo(v1.w) + w2 * bf_lo(v2.w) + w3 * bf_lo(v3.w);
        o[7] += w0 * bf_hi(v0.w) + w1 * bf_hi(v1.w) + w2 * bf_hi(v2.w) + w3 * bf_hi(v3.w);
    }
}

__global__ __launch_bounds__(256) void attn_kernel(
    const unsigned short* __restrict__ q, const unsigned short* __restrict__ kv,
    const unsigned int* __restrict__ mask, float* __restrict__ out)
{
    __shared__ unsigned short nbr[4][PCAP];   // 16KB; per-wave region

    const int tid = threadIdx.x;
    const int lane = tid & 63;
    const int wid = tid >> 6;
    const int row = blockIdx.x * 4 + wid;

    const uint4 qv = *(const uint4*)(q + (size_t)row * DIM + lane * 8);
    const unsigned int* __restrict__ mrow = mask + (size_t)row * MASK_WORDS;

    float o[8];
    #pragma unroll
    for (int i = 0; i < 8; ++i) o[i] = 0.f;
    float l_run = 0.f;
    int degtot = 0;

    #pragma unroll
    for (int ph = 0; ph < 4; ++ph) {
        // phase ph covers nodes [ph*2048, (ph+1)*2048): words ph*64+lane
        unsigned int ww = mrow[ph * 64 + lane];
        int pc = __popc(ww);
        int incl = wave_incl_scan(pc, lane);
        int cn = __shfl(incl, 63, 64);
        degtot += cn;
        if (cn == 0) continue;
        int pos = incl - pc;
        int base = (ph * 64 + lane) * 32;
        while (ww) {
            int b = __ffs(ww) - 1; ww &= ww - 1;
            nbr[wid][pos++] = (unsigned short)(base + b);
        }
        fused_pass(kv, nbr[wid], cn, qv, lane, o, l_run);
    }

    if (degtot == 0) {
        // all-NEG row -> uniform 1/N over all v rows (prob ~0, exactness only)
        #pragma unroll
        for (int i = 0; i < 8; ++i) o[i] = 0.f;
        for (int j = 0; j < N_NODES; ++j) {
            uint4 vv = *(const uint4*)(kv + (size_t)j * KV_STRIDE + DIM + lane * 8);
            o[0] += bf_lo(vv.x); o[1] += bf_hi(vv.x);
            o[2] += bf_lo(vv.y); o[3] += bf_hi(vv.y);
            o[4] += bf_lo(vv.z); o[5] += bf_hi(vv.z);
            o[6] += bf_lo(vv.w); o[7] += bf_hi(vv.w);
        }
        const float sc = 1.0f / N_NODES;
        float4 r0 = {o[0] * sc, o[1] * sc, o[2] * sc, o[3] * sc};
        float4 r1 = {o[4] * sc, o[5] * sc, o[6] * sc, o[7] * sc};
        *(float4*)(out + (size_t)row * DIM + lane * 8) = r0;
        *(float4*)(out + (size_t)row * DIM + lane * 8 + 4) = r1;
        return;
    }

    const float inv = 1.0f / l_run;
    float4 r0 = {o[0] * inv, o[1] * inv, o[2] * inv, o[3] * inv};
    float4 r1 = {o[4] * inv, o[5] * inv, o[6] * inv, o[7] * inv};
    *(float4*)(out + (size_t)row * DIM + lane * 8) = r0;
    *(float4*)(out + (size_t)row * DIM + lane * 8 + 4) = r1;
}

// ---------------------------------------------------------------------------
extern "C" void kernel_launch(void* const* d_in, const int* in_sizes, int n_in,
                              void* d_out, int out_size, void* d_ws, size_t ws_size,
                              hipStream_t stream)
{
    const float* x  = (const float*)d_in[0];
    const int*   ei = (const int*)d_in[1];
    const float* Wq = (const float*)d_in[2];
    const float* bq = (const float*)d_in[3];
    const float* Wk = (const float*)d_in[4];
    const float* bk = (const float*)d_in[5];
    const float* Wv = (const float*)d_in[6];
    const float* bv = (const float*)d_in[7];
    float* out = (float*)d_out;

    const int E = in_sizes[1] / 2;
    const size_t NM = (size_t)N_NODES * DIM;

    // ws: xb (8MB) | Wt (1.5MB) | qb (8MB) | kv interleaved (16MB) | mask (8MB)
    unsigned short* xb = (unsigned short*)d_ws;
    unsigned short* Wt = xb + NM;
    unsigned short* qb = Wt + (size_t)3 * DIM * DIM;
    unsigned short* kv = qb + NM;
    unsigned int* mask = (unsigned int*)(kv + (size_t)N_NODES * KV_STRIDE);

    prep1<<<4864, 256, 0, stream>>>(x, xb, Wq, Wk, Wv, Wt, mask);

    gemm_scatter<<<768 + (E + 255) / 256, 256, 0, stream>>>(
        xb, Wt, bq, bk, bv, qb, kv, ei, mask, E);

    attn_kernel<<<N_NODES / 4, 256, 0, stream>>>(qb, kv, mask, out);
}